// Round 4
// baseline (35473.257 us; speedup 1.0000x reference)
//
#include <hip/hip_runtime.h>
#include <hip/hip_bf16.h>
#include <hip/hip_fp16.h>

typedef _Float16 f16;
typedef __attribute__((ext_vector_type(8))) _Float16 f16x8;
typedef __attribute__((ext_vector_type(4))) float f32x4;

#define T_ 512
#define B_ 128
#define I_ 256
#define H_ 512
#define G3_ 1536
#define KC2 832     // Wc2 cols: [0,512) W_hh | 512 b_hh | (512,544) 0 | [544,800) W_ih | 800 b_ih | rest 0
#define XOFF 544
#define KA2 544     // Wat2 cols: [0,512) W_att | 512 b_att | rest 0
#define HROW 552    // LDS h row: 544 + 8 pad (1104 B, 16B-aligned stride)

#define MFMA16(a,b,c) __builtin_amdgcn_mfma_f32_16x16x32_f16((a),(b),(c),0,0,0)

__device__ __forceinline__ float fast_exp(float x){
  return __builtin_amdgcn_exp2f(x * 1.4426950408889634f);
}
__device__ __forceinline__ float sigm(float x){
  return __builtin_amdgcn_rcpf(1.f + fast_exp(-x));
}
__device__ __forceinline__ float tanh_f(float x){
  return 1.f - 2.f * __builtin_amdgcn_rcpf(1.f + fast_exp(2.f * x));
}

// ---------------- prep: combined fp16 weights with bias columns folded in ----------------
__global__ void k_prep(const float* __restrict__ Wih, const float* __restrict__ Whh,
                       const float* __restrict__ bih, const float* __restrict__ bhh,
                       const float* __restrict__ Watt, const float* __restrict__ batt,
                       f16* __restrict__ Wc2, f16* __restrict__ Wat2){
  const int n1 = G3_ * KC2;
  const int n2 = H_ * KA2;
  const int tot = n1 + n2;
  for (int i = blockIdx.x * blockDim.x + threadIdx.x; i < tot; i += gridDim.x * blockDim.x){
    if (i < n1){
      int r = i / KC2, k = i % KC2;
      float v;
      if      (k <  H_)   v = Whh[r * H_ + k];
      else if (k == H_)   v = bhh[r];
      else if (k <  XOFF) v = 0.f;
      else if (k <  800)  v = Wih[r * I_ + (k - XOFF)];
      else if (k == 800)  v = bih[r];
      else                v = 0.f;
      Wc2[i] = (f16)v;
    } else {
      int j = i - n1; int r = j / KA2, k = j % KA2;
      float v = (k < H_) ? Watt[r * H_ + k] : (k == H_ ? batt[r] : 0.f);
      Wat2[j] = (f16)v;
    }
  }
}

// ---------------- probe: discover the true (lane,reg)->(row,col) D mapping ----------------
__global__ void k_probe(int* __restrict__ rtab, int* __restrict__ ctab){
  __shared__ __align__(16) f16 A[16][32];
  __shared__ __align__(16) f16 BT[16][32];
  const int l = threadIdx.x, l16 = l & 15, lg = l >> 4;
  for (int i = l; i < 512; i += 64){ ((f16*)A)[i] = (f16)0.f; ((f16*)BT)[i] = (f16)0.f; }
  __syncthreads();
  if (l < 16){
    A[l][0]  = (f16)(float)(16 * l);
    A[l][1]  = (f16)1.f;
    BT[l][0] = (f16)1.f;
    BT[l][1] = (f16)(float)l;
  }
  __syncthreads();
  f16x8 a = *(const f16x8*)&A[l16][lg * 8];
  f16x8 b = *(const f16x8*)&BT[l16][lg * 8];
  f32x4 z; z[0]=0.f; z[1]=0.f; z[2]=0.f; z[3]=0.f;
  f32x4 d = MFMA16(a, b, z);
  #pragma unroll
  for (int q = 0; q < 4; ++q){
    int code = (int)(d[q] + 0.5f);
    rtab[l * 4 + q] = code >> 4;
    ctab[l * 4 + q] = code & 15;
  }
}

// ---------------- recurrence: 8 WGs x 16 batch rows, persistent over T ----------------
__global__ __launch_bounds__(512) void k_rec(const float* __restrict__ x,
    const f16* __restrict__ Wc2, const int* __restrict__ rtab, const int* __restrict__ ctab,
    f16* __restrict__ hs){
  const int b0   = blockIdx.x * 16;
  const int tid  = threadIdx.x;
  const int wave = tid >> 6;
  const int lane = tid & 63;
  const int l16  = lane & 15;
  const int lg   = lane >> 4;

  __shared__ __align__(16) f16 h16[2][16][HROW];
  for (int i = tid; i < 2 * 16 * HROW; i += 512) ((f16*)h16)[i] = (f16)0.f;
  __syncthreads();
  if (tid < 32) h16[tid >> 4][tid & 15][H_] = (f16)1.f;   // bias-tile "1" at k=512
  __syncthreads();

  int rt[4], ct[4];
  #pragma unroll
  for (int q = 0; q < 4; ++q){ rt[q] = rtab[lane*4+q]; ct[q] = ctab[lane*4+q]; }

  float hold[4][4];
  #pragma unroll
  for (int jt = 0; jt < 4; ++jt)
    #pragma unroll
    for (int q = 0; q < 4; ++q) hold[jt][q] = 0.f;

  f16x8 axb;
  #pragma unroll
  for (int e = 0; e < 8; ++e) axb[e] = (f16)0.f;
  if (lg == 0) axb[0] = (f16)1.f;   // x-bias tile: 1 at logical k-slot 0 of the tile

  const f16*  wptr  = Wc2 + (size_t)l16 * KC2 + lg * 8;
  const float* xbase = x + (size_t)(b0 + l16) * T_ * I_ + lg * 8;

  for (int t = 0; t < T_; ++t){
    const int cur = t & 1, nxt = cur ^ 1;

    f16x8 ax[9];
    {
      const float* xrow = xbase + (size_t)t * I_;
      #pragma unroll
      for (int kx = 0; kx < 8; ++kx){
        f32x4 v0 = *(const f32x4*)(xrow + kx * 32);
        f32x4 v1 = *(const f32x4*)(xrow + kx * 32 + 4);
        f16x8 a;
        a[0]=(f16)v0[0]; a[1]=(f16)v0[1]; a[2]=(f16)v0[2]; a[3]=(f16)v0[3];
        a[4]=(f16)v1[0]; a[5]=(f16)v1[1]; a[6]=(f16)v1[2]; a[7]=(f16)v1[3];
        ax[kx] = a;
      }
      ax[8] = axb;
    }

    f32x4 accR[4], accZ[4], accNh[4], accNx[4];
    #pragma unroll
    for (int jt = 0; jt < 4; ++jt){
      #pragma unroll
      for (int q = 0; q < 4; ++q){
        accR[jt][q] = 0.f; accZ[jt][q] = 0.f; accNh[jt][q] = 0.f; accNx[jt][q] = 0.f;
      }
    }

    // h-part + h-bias tile: kt = 0..16 (k in [0,544) of Wc2)
    #pragma unroll 4
    for (int kt = 0; kt < 17; ++kt){
      f16x8 a = *(const f16x8*)&h16[cur][l16][kt * 32 + lg * 8];
      f16x8 bb[12];
      #pragma unroll
      for (int jt = 0; jt < 4; ++jt){
        size_t nr = (size_t)(wave * 64 + jt * 16);
        bb[jt*3+0] = *(const f16x8*)(wptr + nr * KC2            + kt * 32);
        bb[jt*3+1] = *(const f16x8*)(wptr + (nr + H_)   * KC2   + kt * 32);
        bb[jt*3+2] = *(const f16x8*)(wptr + (nr + 2*H_) * KC2   + kt * 32);
      }
      #pragma unroll
      for (int jt = 0; jt < 4; ++jt){
        accR[jt]  = MFMA16(a, bb[jt*3+0], accR[jt]);
        accZ[jt]  = MFMA16(a, bb[jt*3+1], accZ[jt]);
        accNh[jt] = MFMA16(a, bb[jt*3+2], accNh[jt]);
      }
    }
    // x-part + x-bias tile: kx = 0..8 (k in [544,832) of Wc2)
    #pragma unroll 3
    for (int kx = 0; kx < 9; ++kx){
      f16x8 a = ax[kx];
      f16x8 bb[12];
      #pragma unroll
      for (int jt = 0; jt < 4; ++jt){
        size_t nr = (size_t)(wave * 64 + jt * 16);
        bb[jt*3+0] = *(const f16x8*)(wptr + nr * KC2            + XOFF + kx * 32);
        bb[jt*3+1] = *(const f16x8*)(wptr + (nr + H_)   * KC2   + XOFF + kx * 32);
        bb[jt*3+2] = *(const f16x8*)(wptr + (nr + 2*H_) * KC2   + XOFF + kx * 32);
      }
      #pragma unroll
      for (int jt = 0; jt < 4; ++jt){
        accR[jt]  = MFMA16(a, bb[jt*3+0], accR[jt]);
        accZ[jt]  = MFMA16(a, bb[jt*3+1], accZ[jt]);
        accNx[jt] = MFMA16(a, bb[jt*3+2], accNx[jt]);
      }
    }

    // epilogue: all math is slot-local (biases folded); writes use probe tables
    #pragma unroll
    for (int jt = 0; jt < 4; ++jt){
      #pragma unroll
      for (int q = 0; q < 4; ++q){
        float r  = sigm(accR[jt][q]);
        float z  = sigm(accZ[jt][q]);
        float nn = tanh_f(accNx[jt][q] + r * accNh[jt][q]);
        float h  = (1.f - z) * nn + z * hold[jt][q];
        hold[jt][q] = h;
        int rw = rt[q];
        int c  = wave * 64 + jt * 16 + ct[q];
        f16 hh = (f16)h;
        h16[nxt][rw][c] = hh;
        hs[((size_t)t * B_ + b0 + rw) * H_ + c] = hh;
      }
    }
    __syncthreads();
  }
}

// ---------------- scores: S = tanh(hs @ W_att^T + b_att) (bias folded), fp16 ----------------
__global__ __launch_bounds__(256) void k_scores(const f16* __restrict__ hs,
    const f16* __restrict__ Wat2, const int* __restrict__ rtab, const int* __restrict__ ctab,
    f16* __restrict__ S){
  const int wg   = blockIdx.x;
  const int mblk = wg >> 2;
  const int nblk = wg & 3;
  const int tid  = threadIdx.x;
  const int wv   = tid >> 6, lane = tid & 63, l16 = lane & 15, lg = lane >> 4;
  const int R0   = mblk * 256;

  int rt[4], ct[4];
  #pragma unroll
  for (int q = 0; q < 4; ++q){ rt[q] = rtab[lane*4+q]; ct[q] = ctab[lane*4+q]; }

  f16x8 ab;
  #pragma unroll
  for (int e = 0; e < 8; ++e) ab[e] = (f16)0.f;
  if (lg == 0) ab[0] = (f16)1.f;

  f32x4 acc[4][8];
  #pragma unroll
  for (int mt = 0; mt < 4; ++mt)
    #pragma unroll
    for (int nt = 0; nt < 8; ++nt){
      #pragma unroll
      for (int q = 0; q < 4; ++q) acc[mt][nt][q] = 0.f;
    }

  for (int kt = 0; kt < 17; ++kt){
    f16x8 a[4];
    if (kt < 16){
      #pragma unroll
      for (int mt = 0; mt < 4; ++mt)
        a[mt] = *(const f16x8*)&hs[(size_t)(R0 + (wv + mt*4) * 16 + l16) * H_ + kt * 32 + lg * 8];
    } else {
      #pragma unroll
      for (int mt = 0; mt < 4; ++mt) a[mt] = ab;
    }
    #pragma unroll
    for (int nt = 0; nt < 8; ++nt){
      f16x8 b = *(const f16x8*)&Wat2[(size_t)(nblk * 128 + nt * 16 + l16) * KA2 + kt * 32 + lg * 8];
      #pragma unroll
      for (int mt = 0; mt < 4; ++mt)
        acc[mt][nt] = MFMA16(a[mt], b, acc[mt][nt]);
    }
  }

  #pragma unroll
  for (int nt = 0; nt < 8; ++nt){
    #pragma unroll
    for (int mt = 0; mt < 4; ++mt){
      #pragma unroll
      for (int q = 0; q < 4; ++q){
        float s = tanh_f(acc[mt][nt][q]);
        int row = R0 + (wv + mt*4) * 16 + rt[q];
        int col = nblk * 128 + nt * 16 + ct[q];
        S[(size_t)row * H_ + col] = (f16)s;
      }
    }
  }
}

// ---------------- pooling: softmax over t (|s|<1, no max pass) + weighted sum ----------------
// OUTPUT IS FP32 (reference returns float32; harness: "else float*")
__global__ __launch_bounds__(256) void k_pool(const f16* __restrict__ hs,
    const f16* __restrict__ S, float* __restrict__ out){
  const int b = blockIdx.x >> 1;
  const int j = (blockIdx.x & 1) * 256 + threadIdx.x;
  float num = 0.f, den = 0.f;
  for (int t = 0; t < T_; ++t){
    size_t idx = ((size_t)t * B_ + b) * H_ + j;
    float s = (float)S[idx];
    float h = (float)hs[idx];
    float e = fast_exp(s);
    num = fmaf(e, h, num);
    den += e;
  }
  out[b * H_ + j] = num / den;
}

extern "C" void kernel_launch(void* const* d_in, const int* in_sizes, int n_in,
                              void* d_out, int out_size, void* d_ws, size_t ws_size,
                              hipStream_t stream){
  (void)in_sizes; (void)n_in; (void)out_size;
  const float* x    = (const float*)d_in[0];
  const float* Wih  = (const float*)d_in[1];
  const float* Whh  = (const float*)d_in[2];
  const float* bih  = (const float*)d_in[3];
  const float* bhh  = (const float*)d_in[4];
  const float* Watt = (const float*)d_in[5];
  const float* batt = (const float*)d_in[6];

  char* ws = (char*)d_ws;
  // layout (bytes):
  //   hs  : [T][B][H] fp16   @ 0           (67,108,864)
  //   S   : [T][B][H] fp16   @ 67,108,864  (67,108,864)
  //   Wc2 : [1536][832] fp16 @ 134,217,728 (2,555,904)
  //   Wat2: [512][544] fp16  @ 136,773,632 (557,056)
  //   rtab: int[256]         @ 137,330,688 (1,024)
  //   ctab: int[256]         @ 137,331,712 (1,024)
  const size_t NEED = 137332736ull;
  if (ws_size < NEED) return;  // signature: absmax would be exactly 0.12451 (zeros)

  f16* hs   = (f16*)ws;
  f16* S    = (f16*)(ws + 67108864ull);
  f16* Wc2  = (f16*)(ws + 134217728ull);
  f16* Wat2 = (f16*)(ws + 136773632ull);
  int* rtab = (int*)(ws + 137330688ull);
  int* ctab = (int*)(ws + 137331712ull);

  k_prep  <<<1024, 256, 0, stream>>>(Wih, Whh, bih, bhh, Watt, batt, Wc2, Wat2);
  k_probe <<<1,    64,  0, stream>>>(rtab, ctab);
  k_rec   <<<8,    512, 0, stream>>>(x, Wc2, rtab, ctab, hs);
  k_scores<<<1024, 256, 0, stream>>>(hs, Wat2, rtab, ctab, S);
  k_pool  <<<256,  256, 0, stream>>>(hs, S, (float*)d_out);
}

// Round 5
// 10511.363 us; speedup vs baseline: 3.3748x; 3.3748x over previous
//
#include <hip/hip_runtime.h>
#include <hip/hip_bf16.h>
#include <hip/hip_fp16.h>

typedef _Float16 f16;
typedef __attribute__((ext_vector_type(8))) _Float16 f16x8;
typedef __attribute__((ext_vector_type(4))) float f32x4;

#define T_ 512
#define B_ 128
#define I_ 256
#define H_ 512
#define G3_ 1536
#define KC2 832     // Wc2 cols: [0,512) W_hh | 512 b_hh | (512,544) 0 | [544,800) W_ih | 800 b_ih | rest 0
#define XOFF 544
#define KA2 544     // Wat2 cols: [0,512) W_att | 512 b_att | rest 0
#define WLP 840     // LDS weight row pitch (832 + 8): stride 420 words = 4 mod 32 banks -> 2-way only

#define MFMA16(a,b,c) __builtin_amdgcn_mfma_f32_16x16x32_f16((a),(b),(c),0,0,0)

__device__ __forceinline__ float fast_exp(float x){
  return __builtin_amdgcn_exp2f(x * 1.4426950408889634f);
}
__device__ __forceinline__ float sigm(float x){
  return __builtin_amdgcn_rcpf(1.f + fast_exp(-x));
}
__device__ __forceinline__ float tanh_f(float x){
  return 1.f - 2.f * __builtin_amdgcn_rcpf(1.f + fast_exp(2.f * x));
}

// ---------------- prep: fp16 weights (biases folded as extra K-columns) + fp16 x ----------------
__global__ void k_prep(const float* __restrict__ x, const float* __restrict__ Wih,
                       const float* __restrict__ Whh,
                       const float* __restrict__ bih, const float* __restrict__ bhh,
                       const float* __restrict__ Watt, const float* __restrict__ batt,
                       f16* __restrict__ Wc2, f16* __restrict__ Wat2, f16* __restrict__ x16){
  const int n1 = G3_ * KC2;
  const int n2 = H_ * KA2;
  const int n3 = B_ * T_ * I_;
  const int tot = n1 + n2 + n3;
  for (int i = blockIdx.x * blockDim.x + threadIdx.x; i < tot; i += gridDim.x * blockDim.x){
    if (i < n1){
      int r = i / KC2, k = i % KC2;
      float v;
      if      (k <  H_)   v = Whh[r * H_ + k];
      else if (k == H_)   v = bhh[r];
      else if (k <  XOFF) v = 0.f;
      else if (k <  800)  v = Wih[r * I_ + (k - XOFF)];
      else if (k == 800)  v = bih[r];
      else                v = 0.f;
      Wc2[i] = (f16)v;
    } else if (i < n1 + n2){
      int j = i - n1; int r = j / KA2, k = j % KA2;
      float v = (k < H_) ? Watt[r * H_ + k] : (k == H_ ? batt[r] : 0.f);
      Wat2[j] = (f16)v;
    } else {
      int j = i - n1 - n2;
      x16[j] = (f16)x[j];      // same [B][T][I] flat order
    }
  }
}

// ---------------- probe: (lane,reg)->(row,col) D mapping, same load pattern as main kernels ----------------
__global__ void k_probe(int* __restrict__ rtab, int* __restrict__ ctab){
  __shared__ __align__(16) f16 A[16][32];
  __shared__ __align__(16) f16 BT[16][32];
  const int l = threadIdx.x, l16 = l & 15, lg = l >> 4;
  for (int i = l; i < 512; i += 64){ ((f16*)A)[i] = (f16)0.f; ((f16*)BT)[i] = (f16)0.f; }
  __syncthreads();
  if (l < 16){
    A[l][0]  = (f16)(float)(16 * l);
    A[l][1]  = (f16)1.f;
    BT[l][0] = (f16)1.f;
    BT[l][1] = (f16)(float)l;
  }
  __syncthreads();
  f16x8 a = *(const f16x8*)&A[l16][lg * 8];
  f16x8 b = *(const f16x8*)&BT[l16][lg * 8];
  f32x4 z; z[0]=0.f; z[1]=0.f; z[2]=0.f; z[3]=0.f;
  f32x4 d = MFMA16(a, b, z);
  #pragma unroll
  for (int q = 0; q < 4; ++q){
    int code = (int)(d[q] + 0.5f);
    rtab[l * 4 + q] = code >> 4;
    ctab[l * 4 + q] = code & 15;
  }
}

// ---------------- recurrence: 256 cooperative WGs (8 batch-groups x 32 col-WGs), LDS-resident weights ----
// WG (g = bid&7, c = bid>>3): batch rows [16g,16g+16), h-cols [16c,16c+16).
// h double-buffered in global: h_buf[2][8][16][512] f16; step t writes parity t&1, reads parity (t-1)&1.
// Per-group barrier: monotonic counter cnt[g*16], target 32*(t+1).
__global__ __launch_bounds__(64, 1) void k_rec(const f16* __restrict__ x16,
    const f16* __restrict__ Wc2, const int* __restrict__ rtab, const int* __restrict__ ctab,
    f16* __restrict__ h_buf, unsigned int* __restrict__ cnt, f16* __restrict__ hs){
  const int bid = blockIdx.x;
  const int g   = bid & 7;
  const int c   = bid >> 3;
  const int b0  = g * 16;
  const int j0  = c * 16;
  const int lane = threadIdx.x;
  const int l16  = lane & 15;
  const int lg   = lane >> 4;

  __shared__ __align__(16) f16 Wl[3][16][WLP];

  // stage this WG's weight slice: 3 gates x 16 rows x 832 cols (78 KB), once
  for (int idx = lane; idx < 48 * 104; idx += 64){
    int row = idx / 104, ch = idx % 104;
    int gi = row >> 4, i = row & 15;
    const f16* src = Wc2 + (size_t)(gi * H_ + j0 + i) * KC2 + ch * 8;
    *(f16x8*)&Wl[gi][i][ch * 8] = *(const f16x8*)src;
  }

  int rt[4], ct[4];
  #pragma unroll
  for (int q = 0; q < 4; ++q){ rt[q] = rtab[lane*4+q]; ct[q] = ctab[lane*4+q]; }

  float hold[4];
  #pragma unroll
  for (int q = 0; q < 4; ++q) hold[q] = 0.f;

  f16x8 ones;
  #pragma unroll
  for (int e = 0; e < 8; ++e) ones[e] = (f16)0.f;
  if (lg == 0) ones[0] = (f16)1.f;   // A-frag with 1 at the tile's first k-slot

  __syncthreads();

  const f16* xb = x16 + (size_t)(b0 + l16) * T_ * I_ + lg * 8;
  unsigned int* cptr = cnt + g * 16;

  for (int t = 0; t < T_; ++t){
    const f16* hread = h_buf + (((size_t)((t & 1) ^ 1) * 8 + g) * 16 + l16) * H_ + lg * 8;

    f32x4 aR, aZ, aNh, aNx;
    #pragma unroll
    for (int q = 0; q < 4; ++q){ aR[q]=0.f; aZ[q]=0.f; aNh[q]=0.f; aNx[q]=0.f; }

    // h-part: k in [0,512)
    #pragma unroll 4
    for (int kt = 0; kt < 16; ++kt){
      f16x8 a  = *(const f16x8*)(hread + kt * 32);
      f16x8 w0 = *(const f16x8*)&Wl[0][l16][kt*32 + lg*8];
      f16x8 w1 = *(const f16x8*)&Wl[1][l16][kt*32 + lg*8];
      f16x8 w2 = *(const f16x8*)&Wl[2][l16][kt*32 + lg*8];
      aR  = MFMA16(a, w0, aR);
      aZ  = MFMA16(a, w1, aZ);
      aNh = MFMA16(a, w2, aNh);
    }
    // h-bias tile: k in [512,544), b_hh at col 512
    {
      f16x8 w0 = *(const f16x8*)&Wl[0][l16][512 + lg*8];
      f16x8 w1 = *(const f16x8*)&Wl[1][l16][512 + lg*8];
      f16x8 w2 = *(const f16x8*)&Wl[2][l16][512 + lg*8];
      aR  = MFMA16(ones, w0, aR);
      aZ  = MFMA16(ones, w1, aZ);
      aNh = MFMA16(ones, w2, aNh);
    }
    // x-part: k in [544,800)
    const f16* xrow = xb + (size_t)t * I_;
    #pragma unroll 4
    for (int kx = 0; kx < 8; ++kx){
      f16x8 a  = *(const f16x8*)(xrow + kx * 32);
      f16x8 w0 = *(const f16x8*)&Wl[0][l16][XOFF + kx*32 + lg*8];
      f16x8 w1 = *(const f16x8*)&Wl[1][l16][XOFF + kx*32 + lg*8];
      f16x8 w2 = *(const f16x8*)&Wl[2][l16][XOFF + kx*32 + lg*8];
      aR  = MFMA16(a, w0, aR);
      aZ  = MFMA16(a, w1, aZ);
      aNx = MFMA16(a, w2, aNx);
    }
    // x-bias tile: k in [800,832), b_ih at col 800
    {
      f16x8 w0 = *(const f16x8*)&Wl[0][l16][800 + lg*8];
      f16x8 w1 = *(const f16x8*)&Wl[1][l16][800 + lg*8];
      f16x8 w2 = *(const f16x8*)&Wl[2][l16][800 + lg*8];
      aR  = MFMA16(ones, w0, aR);
      aZ  = MFMA16(ones, w1, aZ);
      aNx = MFMA16(ones, w2, aNx);
    }

    // epilogue: gates, state update, publish h tile
    f16* hwr = h_buf + (((size_t)(t & 1) * 8 + g) * 16) * H_;
    #pragma unroll
    for (int q = 0; q < 4; ++q){
      float r  = sigm(aR[q]);
      float z  = sigm(aZ[q]);
      float nn = tanh_f(aNx[q] + r * aNh[q]);
      float h  = (1.f - z) * nn + z * hold[q];
      hold[q] = h;
      f16 hh = (f16)h;
      int rw = rt[q];
      int cc = j0 + ct[q];
      hwr[(size_t)rw * H_ + cc] = hh;
      hs[((size_t)t * B_ + b0 + rw) * H_ + cc] = hh;
    }

    if (t < T_ - 1){
      __threadfence();
      if (lane == 0){
        __hip_atomic_fetch_add(cptr, 1u, __ATOMIC_RELEASE, __HIP_MEMORY_SCOPE_AGENT);
        const unsigned int tgt = 32u * (unsigned)(t + 1);
        while (__hip_atomic_load(cptr, __ATOMIC_ACQUIRE, __HIP_MEMORY_SCOPE_AGENT) < tgt){
          __builtin_amdgcn_s_sleep(1);
        }
      }
      __syncthreads();
      __threadfence();
    }
  }
}

// ---------------- fused attention: S = tanh(hs@Watt^T + b), softmax over t, weighted sum ----------------
// 128 WGs (one per batch row b), 4 waves; wave wv owns j-cols [wv*128, wv*128+128).
__global__ __launch_bounds__(256, 1) void k_att(const f16* __restrict__ hs,
    const f16* __restrict__ Wat2, const int* __restrict__ rtab, const int* __restrict__ ctab,
    float* __restrict__ out){
  const int b   = blockIdx.x;
  const int tid = threadIdx.x;
  const int wv  = tid >> 6, lane = tid & 63, l16 = lane & 15, lg = lane >> 4;

  __shared__ float numl[H_], denl[H_];
  for (int i = tid; i < H_; i += 256){ numl[i] = 0.f; denl[i] = 0.f; }
  __syncthreads();

  int rt[4], ct[4];
  #pragma unroll
  for (int q = 0; q < 4; ++q){ rt[q] = rtab[lane*4+q]; ct[q] = ctab[lane*4+q]; }

  f16x8 ones;
  #pragma unroll
  for (int e = 0; e < 8; ++e) ones[e] = (f16)0.f;
  if (lg == 0) ones[0] = (f16)1.f;

  const int jb = wv * 128;

  for (int nt = 0; nt < 8; ++nt){
    // preload the 17 B-fragments for this 16-col tile (incl. bias tile at k=512)
    f16x8 bf[17];
    #pragma unroll
    for (int kt = 0; kt < 17; ++kt)
      bf[kt] = *(const f16x8*)&Wat2[(size_t)(jb + nt*16 + l16) * KA2 + kt*32 + lg*8];

    float numP[4], denP[4];
    #pragma unroll
    for (int q = 0; q < 4; ++q){ numP[q] = 0.f; denP[q] = 0.f; }

    for (int tt = 0; tt < 32; ++tt){
      f32x4 acc;
      #pragma unroll
      for (int q = 0; q < 4; ++q) acc[q] = 0.f;
      const f16* arow = hs + ((size_t)(tt*16 + l16) * B_ + b) * H_ + lg*8;
      #pragma unroll
      for (int kt = 0; kt < 16; ++kt){
        f16x8 a = *(const f16x8*)(arow + kt * 32);
        acc = MFMA16(a, bf[kt], acc);
      }
      acc = MFMA16(ones, bf[16], acc);
      #pragma unroll
      for (int q = 0; q < 4; ++q){
        float s = tanh_f(acc[q]);
        float e = fast_exp(s);                 // |s|<1: no max-shift needed
        int trow = tt*16 + rt[q];
        int j    = jb + nt*16 + ct[q];
        float hv = (float)hs[((size_t)trow * B_ + b) * H_ + j];
        numP[q] = fmaf(e, hv, numP[q]);
        denP[q] += e;
      }
    }
    #pragma unroll
    for (int q = 0; q < 4; ++q){
      int j = jb + nt*16 + ct[q];
      atomicAdd(&numl[j], numP[q]);
      atomicAdd(&denl[j], denP[q]);
    }
  }
  __syncthreads();
  for (int j = tid; j < H_; j += 256)
    out[(size_t)b * H_ + j] = numl[j] / denl[j];
}

extern "C" void kernel_launch(void* const* d_in, const int* in_sizes, int n_in,
                              void* d_out, int out_size, void* d_ws, size_t ws_size,
                              hipStream_t stream){
  (void)in_sizes; (void)n_in; (void)out_size;
  const float* x    = (const float*)d_in[0];
  const float* Wih  = (const float*)d_in[1];
  const float* Whh  = (const float*)d_in[2];
  const float* bih  = (const float*)d_in[3];
  const float* bhh  = (const float*)d_in[4];
  const float* Watt = (const float*)d_in[5];
  const float* batt = (const float*)d_in[6];

  char* ws = (char*)d_ws;
  // layout (bytes):
  //   hs   : [T][B][H] f16        @ 0            (67,108,864)
  //   x16  : [B][T][I] f16        @ 67,108,864   (33,554,432)
  //   Wc2  : [1536][832] f16      @ 100,663,296  (2,555,904)
  //   Wat2 : [512][544] f16       @ 103,219,200  (557,056)
  //   rtab : int[256]             @ 103,776,256  (1,024)
  //   ctab : int[256]             @ 103,777,280  (1,024)
  //   h_buf: [2][8][16][512] f16  @ 103,778,304  (262,144)
  //   cnt  : uint[8] @64B stride  @ 104,040,448  (512)
  const size_t OFF_HS  = 0ull;
  const size_t OFF_X16 = 67108864ull;
  const size_t OFF_WC2 = 100663296ull;
  const size_t OFF_WAT = 103219200ull;
  const size_t OFF_RT  = 103776256ull;
  const size_t OFF_CT  = 103777280ull;
  const size_t OFF_HB  = 103778304ull;
  const size_t OFF_CNT = 104040448ull;
  const size_t NEED    = 104040960ull;
  if (ws_size < NEED) return;

  f16* hs    = (f16*)(ws + OFF_HS);
  f16* x16   = (f16*)(ws + OFF_X16);
  f16* Wc2   = (f16*)(ws + OFF_WC2);
  f16* Wat2  = (f16*)(ws + OFF_WAT);
  int* rtab  = (int*)(ws + OFF_RT);
  int* ctab  = (int*)(ws + OFF_CT);
  f16* h_buf = (f16*)(ws + OFF_HB);
  unsigned int* cnt = (unsigned int*)(ws + OFF_CNT);

  // zero h (t=-1 state) and the barrier counters — must happen every launch
  hipMemsetAsync(ws + OFF_HB, 0, 262144 + 512, stream);

  k_prep <<<2048, 256, 0, stream>>>(x, Wih, Whh, bih, bhh, Watt, batt, Wc2, Wat2, x16);
  k_probe<<<1,    64,  0, stream>>>(rtab, ctab);

  {
    void* args[] = { (void*)&x16, (void*)&Wc2, (void*)&rtab, (void*)&ctab,
                     (void*)&h_buf, (void*)&cnt, (void*)&hs };
    hipLaunchCooperativeKernel((const void*)k_rec, dim3(256), dim3(64), args, 0, stream);
  }

  k_att<<<128, 256, 0, stream>>>(hs, Wat2, rtab, ctab, (float*)d_out);
}